// Round 2
// baseline (306.355 us; speedup 1.0000x reference)
//
#include <hip/hip_runtime.h>

#define B_DIM 4096
#define T_DIM 200
#define D_DIM 128
#define H_DIM 16
#define TT    64            // t-tile
#define NTILE 4             // ceil(200/64)
#define FSTR  132           // padded floats per LDS facts row (132*4B = 16B-aligned, banks balanced)
#define SMEM_FLOATS (2*TT*FSTR + H_DIM*D_DIM + D_DIM + H_DIM + 512 + TT + 4)

__device__ __forceinline__ float sigmoidf_(float x) { return 1.f / (1.f + __expf(-x)); }

extern "C" __global__ __launch_bounds__(256, 2)
void din_fused(const float* __restrict__ query,
               const float* __restrict__ facts,
               const int* __restrict__ mask,
               const float* __restrict__ W1,
               const float* __restrict__ b1,
               const float* __restrict__ W2,
               float* __restrict__ out)
{
    const int b   = blockIdx.x;
    const int tid = threadIdx.x;
    extern __shared__ __align__(16) float smem[];
    float* fbuf = smem;                       // [2][TT*FSTR] facts tiles (double buffer)
    float* weff = smem + 2*TT*FSTR;           // [H][D] transposed effective weights
    float* qrow = weff + H_DIM*D_DIM;         // [128]
    float* qw   = qrow + D_DIM;               // [16]  per-row bias inside sigmoid
    float* scr  = qw + H_DIM;                 // [512] reduce scratch (aliased uses)
    float* wbuf = scr + 512;                  // [64]  per-tile softmax weights
    float* red  = wbuf + TT;                  // [4]   {tile_max, tile_sum}

    const size_t fbase = (size_t)b * T_DIM * D_DIM;

    // ---- prologue: q row + tile0 prefetch (regs) ----
    if (tid < D_DIM) qrow[tid] = query[(size_t)b * D_DIM + tid];

    float4 r[8];
    #pragma unroll
    for (int k = 0; k < 8; ++k) {
        int f4 = tid + 256 * k;
        int tt = f4 >> 5, cc = f4 & 31;       // tile0: tt<64 < 200, no clamp needed
        r[k] = *(const float4*)&facts[fbase + (size_t)tt * D_DIM + 4 * cc];
    }
    __syncthreads();   // qrow ready

    // ---- W_eff[h][d] = (W1b - W1c)[d][h] + q_d * W1d[d][h] ----
    #pragma unroll
    for (int k = 0; k < 8; ++k) {
        int idx = tid + 256 * k;              // idx = h*128 + d
        int d = idx & 127, h = idx >> 7;
        weff[idx] = W1[(128 + d) * H_DIM + h] - W1[(256 + d) * H_DIM + h]
                  + qrow[d] * W1[(384 + d) * H_DIM + h];
    }
    // qW partials: thread = (h = tid&15, dgroup = tid>>4)
    {
        int h = tid & 15, g = tid >> 4;
        float p = 0.f;
        #pragma unroll
        for (int j = 0; j < 8; ++j) {
            int d = 8 * g + j;
            p += qrow[d] * (W1[d * H_DIM + h] + W1[(256 + d) * H_DIM + h]);
        }
        scr[tid] = p;                         // scr[g*16+h] layout via tid
    }
    // commit tile0 to LDS
    #pragma unroll
    for (int k = 0; k < 8; ++k) {
        int f4 = tid + 256 * k;
        int tt = f4 >> 5, cc = f4 & 31;
        *(float4*)&fbuf[tt * FSTR + 4 * cc] = r[k];
    }
    __syncthreads();   // weff, scr partials, tile0 ready
    if (tid < H_DIM) {
        float s = b1[tid];
        #pragma unroll
        for (int g = 0; g < 16; ++g) s += scr[g * 16 + tid];
        qw[tid] = s;
    }
    __syncthreads();   // qw ready

    const int   t2  = tid & 31;               // scoring: t in {t2, t2+32}
    const int   h2  = tid >> 5;               // scoring: h in {h2, h2+8}
    const float w2a = W2[h2], w2b = W2[h2 + 8];
    const float qwa = qw[h2], qwb = qw[h2 + 8];
    const int   c4  = tid & 31;               // sum phase: float4 column
    const int   tg8 = tid >> 5;               // sum phase: t in [8*tg8, 8*tg8+8)

    float4 acc = make_float4(0.f, 0.f, 0.f, 0.f);
    float m = -3e38f, l = 0.f;
    int cur = 0;

    for (int it = 0; it < NTILE; ++it) {
        const bool pf = (it + 1 < NTILE);
        if (pf) {  // issue next tile's global loads early (latency hides under scoring)
            int t0n = (it + 1) * TT;
            #pragma unroll
            for (int k = 0; k < 8; ++k) {
                int f4 = tid + 256 * k;
                int tt = f4 >> 5, cc = f4 & 31;
                int tg = t0n + tt; if (tg > T_DIM - 1) tg = T_DIM - 1;  // clamp keeps data finite
                r[k] = *(const float4*)&facts[fbase + (size_t)tg * D_DIM + 4 * cc];
            }
        }
        const float* fb = &fbuf[cur * TT * FSTR];

        // ---- scoring: pre[t][h] = qW[h] + f_t . W_eff[h] ----
        float a00 = qwa, a01 = qwb, a10 = qwa, a11 = qwb;
        #pragma unroll 4
        for (int k = 0; k < 32; ++k) {
            float4 f0 = *(const float4*)&fb[t2 * FSTR + 4 * k];
            float4 f1 = *(const float4*)&fb[(t2 + 32) * FSTR + 4 * k];
            float4 wa = *(const float4*)&weff[h2 * D_DIM + 4 * k];
            float4 wb = *(const float4*)&weff[(h2 + 8) * D_DIM + 4 * k];
            a00 += f0.x * wa.x + f0.y * wa.y + f0.z * wa.z + f0.w * wa.w;
            a01 += f0.x * wb.x + f0.y * wb.y + f0.z * wb.z + f0.w * wb.w;
            a10 += f1.x * wa.x + f1.y * wa.y + f1.z * wa.z + f1.w * wa.w;
            a11 += f1.x * wb.x + f1.y * wb.y + f1.z * wb.z + f1.w * wb.w;
        }
        float p0 = sigmoidf_(a00) * w2a + sigmoidf_(a01) * w2b;
        float p1 = sigmoidf_(a10) * w2a + sigmoidf_(a11) * w2b;
        scr[h2 * 64 + t2]      = p0;
        scr[h2 * 64 + t2 + 32] = p1;
        __syncthreads();                              // B1: partials in scr

        if (tid < 64) {   // wave0: finish scores, online-softmax stats
            float s = 0.f;
            #pragma unroll
            for (int hh = 0; hh < 8; ++hh) s += scr[hh * 64 + tid];
            int tglob = it * TT + tid;
            bool valid = (tglob < T_DIM) && (mask[(size_t)b * T_DIM + tglob] != 0);
            s = valid ? s : -1e30f;                   // b2 dropped: softmax shift-invariant
            float mt = s;
            #pragma unroll
            for (int off = 32; off; off >>= 1) mt = fmaxf(mt, __shfl_xor(mt, off));
            float nm = fmaxf(m, mt);
            float wgt = valid ? __expf(s - nm) : 0.f;
            wbuf[tid] = wgt;
            float ss = wgt;
            #pragma unroll
            for (int off = 32; off; off >>= 1) ss += __shfl_xor(ss, off);
            if (tid == 0) { red[0] = mt; red[1] = ss; }
        }
        __syncthreads();                              // B2: wbuf, red ready
        {
            float mt = red[0], S = red[1];
            float nm  = fmaxf(m, mt);
            float fac = __expf(m - nm);               // first tile: exp(-3e38-nm)=0, no NaN
            m = nm;
            l = l * fac + S;
            acc.x *= fac; acc.y *= fac; acc.z *= fac; acc.w *= fac;
        }
        if (pf) {  // commit prefetched tile to other buffer (overlaps with sum phase)
            float* fn = &fbuf[(cur ^ 1) * TT * FSTR];
            #pragma unroll
            for (int k = 0; k < 8; ++k) {
                int f4 = tid + 256 * k;
                int tt = f4 >> 5, cc = f4 & 31;
                *(float4*)&fn[tt * FSTR + 4 * cc] = r[k];
            }
        }
        // ---- weighted sum from resident tile ----
        #pragma unroll
        for (int j = 0; j < 8; ++j) {
            int tt = 8 * tg8 + j;
            float wgt = wbuf[tt];
            float4 f = *(const float4*)&fb[tt * FSTR + 4 * c4];
            acc.x += wgt * f.x; acc.y += wgt * f.y; acc.z += wgt * f.z; acc.w += wgt * f.w;
        }
        __syncthreads();                              // B3: tile consumed, buffers safe
        cur ^= 1;
    }

    // ---- epilogue: combine 8 t-group partials, divide by l ----
    float4 a = acc;
    a.x += __shfl_xor(a.x, 32);
    a.y += __shfl_xor(a.y, 32);
    a.z += __shfl_xor(a.z, 32);
    a.w += __shfl_xor(a.w, 32);
    int wv = tid >> 6, lane = tid & 63;
    if (lane < 32) *(float4*)&scr[wv * 128 + 4 * lane] = a;
    __syncthreads();
    if (tid < D_DIM) {
        float o = scr[tid] + scr[128 + tid] + scr[256 + tid] + scr[384 + tid];
        out[(size_t)b * D_DIM + tid] = o / l;
    }
}

extern "C" void kernel_launch(void* const* d_in, const int* in_sizes, int n_in,
                              void* d_out, int out_size, void* d_ws, size_t ws_size,
                              hipStream_t stream) {
    const float* query = (const float*)d_in[0];
    const float* facts = (const float*)d_in[1];
    const int*   mask  = (const int*)d_in[2];     // harness delivers bool as int32
    const float* W1    = (const float*)d_in[3];
    const float* b1    = (const float*)d_in[4];
    const float* W2    = (const float*)d_in[5];
    // d_in[6] = b2: dropped (softmax shift-invariant)
    float* out = (float*)d_out;
    (void)in_sizes; (void)n_in; (void)out_size; (void)d_ws; (void)ws_size;

    size_t smem_bytes = SMEM_FLOATS * sizeof(float);   // 78,672 B -> 2 blocks/CU
    hipFuncSetAttribute((const void*)din_fused,
                        hipFuncAttributeMaxDynamicSharedMemorySize, (int)smem_bytes);
    din_fused<<<dim3(B_DIM), dim3(256), smem_bytes, stream>>>(
        query, facts, mask, W1, b1, W2, out);
}